// Round 9
// baseline (742.757 us; speedup 1.0000x reference)
//
#include <hip/hip_runtime.h>
#include <math.h>

#define B_  64
#define S_  128
#define LW_ 20
#define CHAR_E_ 30
#define CHAR_C_ 30
#define WORD_E_ 300
#define H_  256
#define NC_ 25
#define F_  330
#define KP_ 352       // K padded to multiple of 32
#define G4_ 1024      // 4*H
#define NG_ 2048      // both directions' gates

typedef __attribute__((ext_vector_type(8))) short short8;
typedef __attribute__((ext_vector_type(4))) float floatx4;
typedef __attribute__((ext_vector_type(8))) int int8v;

__device__ __forceinline__ unsigned int f2bf(float f){
    unsigned int u = __float_as_uint(f);
    u += 0x7FFFu + ((u>>16)&1u);
    return (u>>16) & 0xFFFFu;
}
__device__ __forceinline__ float bf2f(unsigned int v){ return __uint_as_float(v<<16); }

// halfword g (0..3) of a uint2 holding 4 bf16 -> float (g literal -> pure shifts)
__device__ __forceinline__ float bfh(uint2 pk, int g){
    unsigned int w = (g < 2) ? pk.x : pk.y;
    return __uint_as_float((g & 1) ? (w & 0xffff0000u) : (w << 16));
}

// fast sigmoid/tanh: v_exp + v_rcp (single-instr trans ops) — verified numerics (R5/R8 pass)
__device__ __forceinline__ float sigf_(float x){ return __builtin_amdgcn_rcpf(1.0f+__expf(-x)); }
__device__ __forceinline__ float tanhf2_(float x){ return 1.0f - 2.0f*__builtin_amdgcn_rcpf(1.0f+__expf(2.0f*x)); }

// async global->LDS, 16B per lane; LDS dest is wave-uniform base + lane*16
__device__ __forceinline__ void gload16(const void* g, void* l){
    __builtin_amdgcn_global_load_lds((const __attribute__((address_space(1))) unsigned int*)g,
                                     (__attribute__((address_space(3))) unsigned int*)l, 16, 0, 0);
}

// LDS-only barrier: does NOT drain vmcnt, so global prefetch loads stay in flight.
#define BAR_LDS() __asm__ volatile("s_waitcnt lgkmcnt(0)\n\ts_barrier" ::: "memory")

// ---------------- merged prep: charconv | wemb | pack | init ----------------
__global__ __launch_bounds__(256) void k_prep(const float* ct, const int* word,
        const float* cw, const float* cb, const float* wt, const int* sent,
        const float* wf, const float* wr, float* out,
        unsigned short* feat, unsigned short* wpack){
    __shared__ __align__(16) float x[8][32][20];
    int blk = blockIdx.x;
    int tid = threadIdx.x;
    if(blk < 1024){
        int tok0 = blk*8;
        for(int e = tid; e < 8*32*20; e += 256){
            int t  = e % 20;
            int ic = (e/20) & 31;
            int tl = e / 640;
            int id = word[(size_t)(tok0+tl)*LW_ + t];
            float v = 0.f;
            if(ic < CHAR_E_ && id != 0) v = ct[(size_t)id*CHAR_E_ + ic];
            x[tl][ic][t] = v;
        }
        __syncthreads();
        if(tid < 240){
            int tl = tid/30, oc = tid%30;
            float acc[22];
            #pragma unroll
            for(int q=0;q<22;q++) acc[q] = 0.f;
            for(int ic=0; ic<CHAR_E_; ic++){
                float w0 = cw[(oc*CHAR_E_+ic)*3+0];
                float w1 = cw[(oc*CHAR_E_+ic)*3+1];
                float w2 = cw[(oc*CHAR_E_+ic)*3+2];
                const float* xr = &x[tl][ic][0];
                #pragma unroll
                for(int t4=0;t4<5;t4++){
                    float4 v = ((const float4*)xr)[t4];
                    int t0 = t4*4;
                    acc[t0+2] += v.x*w0; acc[t0+1] += v.x*w1; acc[t0+0] += v.x*w2;
                    acc[t0+3] += v.y*w0; acc[t0+2] += v.y*w1; acc[t0+1] += v.y*w2;
                    acc[t0+4] += v.z*w0; acc[t0+3] += v.z*w1; acc[t0+2] += v.z*w2;
                    acc[t0+5] += v.w*w0; acc[t0+4] += v.w*w1; acc[t0+3] += v.w*w2;
                }
            }
            float m = -1e30f;
            #pragma unroll
            for(int t=0;t<20;t++){ float v = acc[t+1]; m = fmaxf(m, v); }
            m += cb[oc];
            feat[(size_t)(tok0+tl)*KP_ + WORD_E_ + oc] = (unsigned short)f2bf(m);
        }
    } else if(blk < 1024+2432){
        int idx = (blk-1024)*256 + tid;
        int n = idx / 76, e4 = idx % 76;
        if(e4 < 75){
            float4 v = ((const float4*)(wt + (size_t)sent[n]*WORD_E_))[e4];
            unsigned int lo = f2bf(v.x) | (f2bf(v.y)<<16);
            unsigned int hi = f2bf(v.z) | (f2bf(v.w)<<16);
            uint2 pr; pr.x = lo; pr.y = hi;
            *(uint2*)(feat + (size_t)n*KP_ + e4*4) = pr;
        } else {
            unsigned int* z = (unsigned int*)(feat + (size_t)n*KP_ + 330);
            #pragma unroll
            for(int q=0;q<11;q++) z[q] = 0;
        }
    } else if(blk < 6272){
        int i = (blk-3456)*256 + tid;
        int r = i / KP_, k = i % KP_;
        const float* src = (r < G4_) ? wf : wr;
        int rr = r & (G4_-1);
        wpack[i] = (k < F_) ? (unsigned short)f2bf(src[(size_t)rr*F_ + k]) : 0;
    } else {
        if(tid == 0) *out = 0.f;
    }
}

// ---------------- bf16 MFMA GEMM: gx = feat(8192x352) . wpack(2048x352)^T + bias ----------------
// Output gxb layout matched to 16-wave LSTM consumer (R8-verified):
//   idx = (((dir*128+s)*32 + bgrp)*16 + w16)*128 + bb*64 + u*4 + g
__global__ __launch_bounds__(256) void k_gemm(const unsigned short* A, const unsigned short* Bw,
                                              const float* bf, const float* br, unsigned short* gxb){
    __shared__ __align__(16) unsigned short As[128*32];
    __shared__ __align__(16) unsigned short Bs[128*32];
    int m0 = blockIdx.x*128, n0 = blockIdx.y*128;
    int tid = threadIdx.x;
    int w = tid>>6, lane = tid&63, q = lane>>4, l16 = lane&15;
    int wr = w>>1, wc = w&1;
    int srow0 = w*32 + (lane>>2);
    int scol  = (lane&3)*8;
    floatx4 acc[4][4];
    #pragma unroll
    for(int i=0;i<4;i++)
        #pragma unroll
        for(int j=0;j<4;j++) acc[i][j] = (floatx4){0.f,0.f,0.f,0.f};

    for(int k0=0; k0<KP_; k0+=32){
        __syncthreads();
        gload16(A  + (size_t)(m0+srow0   )*KP_ + k0 + scol, (unsigned short*)As + w*1024      );
        gload16(A  + (size_t)(m0+srow0+16)*KP_ + k0 + scol, (unsigned short*)As + w*1024 + 512);
        gload16(Bw + (size_t)(n0+srow0   )*KP_ + k0 + scol, (unsigned short*)Bs + w*1024      );
        gload16(Bw + (size_t)(n0+srow0+16)*KP_ + k0 + scol, (unsigned short*)Bs + w*1024 + 512);
        __asm__ volatile("s_waitcnt vmcnt(0)" ::: "memory");
        __syncthreads();
        short8 a_[4], b_[4];
        #pragma unroll
        for(int i=0;i<4;i++) a_[i] = *(const short8*)&As[(wr*64 + i*16 + l16)*32 + q*8];
        #pragma unroll
        for(int j=0;j<4;j++) b_[j] = *(const short8*)&Bs[(wc*64 + j*16 + l16)*32 + q*8];
        #pragma unroll
        for(int i=0;i<4;i++)
            #pragma unroll
            for(int j=0;j<4;j++)
                acc[i][j] = __builtin_amdgcn_mfma_f32_16x16x32_bf16(a_[i], b_[j], acc[i][j], 0,0,0);
    }
    // epilogue: m = m0+wr*64+i*16+q*4+r (token), n = n0+wc*64+j*16+l16 (gate col)
    #pragma unroll
    for(int j=0;j<4;j++){
        int n = n0 + wc*64 + j*16 + l16;
        int dirr = n >> 10, grow = n & 1023;
        float bias = dirr ? br[grow] : bf[grow];
        int gg  = grow >> 8;
        int ug  = grow & 255;
        int w16 = ug >> 4, u = ug & 15;
        int ubase = w16*128 + u*4 + gg;
        #pragma unroll
        for(int i=0;i<4;i++){
            int mb = m0 + wr*64 + i*16 + q*4;
            #pragma unroll
            for(int r=0;r<4;r++){
                int m = mb + r;
                int b = m >> 7, s = m & 127;
                size_t idx = ((size_t)((dirr*128 + s)*32 + (b>>1)))*2048
                           + (size_t)(ubase + (b&1)*64);
                gxb[idx] = (unsigned short)f2bf(acc[i][j][r] + bias);
            }
        }
    }
}

// ---------------- one LSTM step: 16-unit wave, row-tile = gate, ki-SPLIT accumulators ----------------
// A rows: g*16 + u. D: col=l16 (batch), row=q*4+r (unit). ki-split: a0/a1 independent ->
// all 8 MFMAs pipeline (no serial K-chain); merged with 16 v_add at scatter.
__device__ __forceinline__ void lstm_step16w(
    const unsigned char* hbb, unsigned char* hpub,
    float* wl, const int8v (*wreg)[2],
    int l16, int q, int lane,
    uint2 gg, float& cc, float* hs_ptr, const float inv_sc)
{
    int8v hb0 = *(const int8v*)&hbb[l16*272 + q*32];
    int8v hb1 = *(const int8v*)&hbb[l16*272 + 128 + q*32];
    floatx4 a0[4], a1[4];
    #pragma unroll
    for(int g=0; g<4; g++){ a0[g] = (floatx4){0.f,0.f,0.f,0.f}; a1[g] = a0[g]; }
    #pragma unroll
    for(int g=0; g<4; g++){
        a0[g] = __builtin_amdgcn_mfma_scale_f32_16x16x128_f8f6f4(wreg[g][0], hb0, a0[g], 0,0,0,0x7F,0,0x7F);
        a1[g] = __builtin_amdgcn_mfma_scale_f32_16x16x128_f8f6f4(wreg[g][1], hb1, a1[g], 0,0,0,0x7F,0,0x7F);
    }
    if(l16 < 2){
        #pragma unroll
        for(int g=0; g<4; g++){
            floatx4 s = a0[g] + a1[g];
            *(floatx4*)&wl[g*32 + l16*16 + q*4] = s;
        }
    }
    // same-wave DS in-order: write then read, no barrier (verified pattern)
    if(lane < 32){
        float iv = wl[0*32 + lane]*inv_sc + bfh(gg,0);
        float fv = wl[1*32 + lane]*inv_sc + bfh(gg,1);
        float gv = wl[2*32 + lane]*inv_sc + bfh(gg,2);
        float ov = wl[3*32 + lane]*inv_sc + bfh(gg,3);
        float cn = sigf_(fv)*cc + sigf_(iv)*tanhf2_(gv);
        cc = cn;
        float hv = sigf_(ov)*tanhf2_(cn);
        *hs_ptr = hv;
        unsigned int d8 = __builtin_amdgcn_cvt_pk_fp8_f32(hv*16.f, hv*16.f, 0u, false) & 0xFFu;
        *hpub = (unsigned char)d8;
    }
    BAR_LDS();   // h(t) published
}

// ---------------- persistent biLSTM: 64 blocks x 1024 threads (16 waves, 4/SIMD) ----------------
__global__ __launch_bounds__(1024,4) void k_lstm_all(const float* whhf, const float* whhr,
        const unsigned short* gxb, float* hseq)
{
    int bid = blockIdx.x;        // 0..63
    int dir = bid >> 5;
    int bgrp = bid & 31;         // batches bgrp*2, bgrp*2+1
    int tid = threadIdx.x;
    int w16  = tid >> 6;         // wave 0..15: units w16*16..w16*16+15
    int lane = tid & 63;
    int q    = lane >> 4;
    int l16  = lane & 15;
    int bb   = lane >> 4;        // (lane<32) cell batch 0..1
    int u    = lane & 15;        // (lane<32) cell unit-in-wave

    __shared__ __align__(16) unsigned char hlds[2][16*272];   // [buf][batchrow][unit] fp8 (rows 2..15 = 0)
    __shared__ __align__(16) float wregion[16*128];           // per-wave [g][2 batch][16 unit] f32

    const float* whh = dir ? whhr : whhf;

    // one-time: pack weight slice as K=128 fp8 A-fragments.
    int8v wreg[4][2];   // 64 VGPRs
    #pragma unroll
    for(int g=0; g<4; g++){
        const float* rp = whh + (size_t)(g*H_ + w16*16 + l16)*H_;
        #pragma unroll
        for(int ki=0; ki<2; ki++){
            const float* p = rp + ki*128 + q*32;
            int8v acc;
            #pragma unroll
            for(int wd=0; wd<8; wd++){
                unsigned int d = 0;
                d = __builtin_amdgcn_cvt_pk_fp8_f32(p[wd*4+0]*64.f, p[wd*4+1]*64.f, d, false);
                d = __builtin_amdgcn_cvt_pk_fp8_f32(p[wd*4+2]*64.f, p[wd*4+3]*64.f, d, true);
                acc[wd] = (int)d;
            }
            wreg[g][ki] = acc;
        }
    }

    for(int i = tid; i < 2*16*272/4; i += 1024) ((unsigned int*)hlds)[i] = 0;
    __syncthreads();

    const float inv_sc = 1.0f/1024.f;   // w x64, h x16
    float cc = 0.f;

    int s0 = dir ? (S_-1) : 0;
    long gstep = dir ? -65536L : 65536L;
    const unsigned short* gp = gxb + ((size_t)((dir*128 + s0)*32 + bgrp))*2048 + w16*128 + lane*4;
    long hstep = dir ? -(long)(B_*H_) : (long)(B_*H_);
    float* hp = hseq + (((size_t)dir*S_ + s0)*B_ + bgrp*2 + bb)*H_ + w16*16 + u;

    float* wl = &wregion[w16*128];
    unsigned char* hpw0 = &hlds[0][bb*272 + w16*16 + u];
    unsigned char* hpw1 = &hlds[1][bb*272 + w16*16 + u];

    uint2 P = *(const uint2*)gp; gp += gstep;
    uint2 Q;

    for(int t=0; t<S_; t+=2){
        // prefetch step t+1's gates (in flight across step A)
        Q = *(const uint2*)gp; gp += gstep;
        lstm_step16w(&hlds[0][0], hpw1, wl, wreg, l16, q, lane, P, cc, hp, inv_sc);
        hp += hstep;
        // prefetch step t+2 (last iter lands 1 s-slot outside slice, inside gxb: harmless)
        P = *(const uint2*)gp; gp += gstep;
        lstm_step16w(&hlds[1][0], hpw0, wl, wreg, l16, q, lane, Q, cc, hp, inv_sc);
        hp += hstep;
    }
}

// ---------------- merged emissions + CRF: one block per batch ----------------
// Phase 1 (all 256 threads): em[s][nc] for this batch into LDS, h staged in 8-row chunks.
// Phase 2 (wave 0 only, no barriers): verified CRF recursion reading em from LDS.
__global__ __launch_bounds__(256) void k_emcrf(const float* hseq, const float* lw, const float* lb,
        const int* tag, const void* mask, const float* st, const float* et, const float* tr, float* out){
    __shared__ __align__(16) float hst[8][516];   // h chunk: 8 s-rows x 512 (+4 pad)
    __shared__ float els[S_][26];                 // emissions (25 used, 26 stride)
    __shared__ float trs[NC_*NC_];
    int b = blockIdx.x, tid = threadIdx.x;
    for(int i=tid;i<NC_*NC_;i+=256) trs[i]=tr[i];
    int sl = tid >> 5;        // s_local 0..7
    int nc = tid & 31;        // nc slot (<25 active)
    float lbv = (nc < NC_) ? lb[nc] : 0.f;
    for(int c=0;c<16;c++){
        int sbase = c*8;
        __syncthreads();   // protect hst reuse (also covers trs on first iter)
        for(int i = tid; i < 1024; i += 256){
            int p = i >> 7, r = i & 127;
            int s = sbase + p;
            const float* src = (r < 64) ? (hseq + (((size_t)0*S_+s)*B_+b)*H_ + r*4)
                                        : (hseq + (((size_t)1*S_+s)*B_+b)*H_ + (r-64)*4);
            *(float4*)&hst[p][r*4] = *(const float4*)src;
        }
        __syncthreads();
        if(nc < NC_){
            const float4* wv = (const float4*)(lw + (size_t)nc*2*H_);
            const float4* hv = (const float4*)&hst[sl][0];
            float acc = lbv;
            #pragma unroll 16
            for(int k=0;k<128;k++){ float4 a=hv[k], ww=wv[k]; acc += a.x*ww.x + a.y*ww.y + a.z*ww.z + a.w*ww.w; }
            els[sbase+sl][nc] = acc;
        }
    }
    __syncthreads();
    if(tid >= 64) return;

    // ---- CRF (single wave, no barriers) ----
    unsigned int first = *(const unsigned int*)mask;
    int ml;  // 0=int32, 1=uint8, 2=float32
    if(first == 1u) ml = 0;
    else if(first == 0x3F800000u) ml = 2;
    else ml = 1;

    // gold path score
    float part = 0.f; int cnt = 0;
    for(int s = tid; s < S_; s += 64){
        float mkv;
        {
            int off = b*S_ + s;
            if(ml==0)      mkv = ((const int*)mask)[off] ? 1.f : 0.f;
            else if(ml==1) mkv = ((const unsigned char*)mask)[off] ? 1.f : 0.f;
            else           mkv = ((const float*)mask)[off];
        }
        cnt += (mkv != 0.f) ? 1 : 0;
        if(s == 0){
            int t0 = tag[b*S_];
            part += st[t0] + els[0][t0];
        } else {
            int tp = tag[b*S_ + s-1], tc = tag[b*S_ + s];
            part += mkv * (trs[tp*NC_ + tc] + els[s][tc]);
        }
    }
    for(int o=32;o>0;o>>=1){ part += __shfl_down(part, o); cnt += __shfl_down(cnt, o); }
    float score = 0.f;
    int len = __shfl(cnt, 0);
    float score0 = __shfl(part, 0);
    if(tid == 0) score = score0 + et[ tag[b*S_ + len-1] ];

    // E columns in registers
    float Ecol[NC_];
    if(tid < NC_){
        #pragma unroll
        for(int i=0;i<NC_;i++) Ecol[i] = __expf(trs[i*NC_+tid]);
    } else {
        #pragma unroll
        for(int i=0;i<NC_;i++) Ecol[i] = 0.f;
    }

    float alpha = (tid < NC_) ? (st[tid] + els[0][tid]) : -1e30f;

    for(int s=1;s<S_;s++){
        float em_c = (tid < NC_) ? els[s][tid] : 0.f;
        float mkv;
        {
            int off = b*S_ + s;
            if(ml==0)      mkv = ((const int*)mask)[off] ? 1.f : 0.f;
            else if(ml==1) mkv = ((const unsigned char*)mask)[off] ? 1.f : 0.f;
            else           mkv = ((const float*)mask)[off];
        }
        float v = alpha;
        #pragma unroll
        for(int o=16;o>0;o>>=1) v = fmaxf(v, __shfl_down(v, o));
        float m = __shfl(v, 0);
        float a = (tid < NC_) ? __expf(alpha - m) : 0.f;
        float S0 = 0.f, S1 = 0.f;
        #pragma unroll
        for(int i=0;i<24;i+=2){ S0 += __shfl(a, i) * Ecol[i]; S1 += __shfl(a, i+1) * Ecol[i+1]; }
        S0 += __shfl(a, 24) * Ecol[24];
        float nxt = m + __logf(S0 + S1) + em_c;
        if(tid < NC_ && mkv != 0.f) alpha = nxt;
    }

    float v = (tid < NC_) ? (alpha + et[tid]) : -1e30f;
    float m2 = v;
    #pragma unroll
    for(int o=16;o>0;o>>=1) m2 = fmaxf(m2, __shfl_down(m2, o));
    m2 = __shfl(m2, 0);
    float e = (tid < NC_) ? __expf(v - m2) : 0.f;
    #pragma unroll
    for(int o=16;o>0;o>>=1) e += __shfl_down(e, o);
    if(tid == 0){
        float logZ = m2 + __logf(e);
        atomicAdd(out, logZ - score);
    }
}

extern "C" void kernel_launch(void* const* d_in, const int* in_sizes, int n_in,
                              void* d_out, int out_size, void* d_ws, size_t ws_size,
                              hipStream_t stream) {
    const float* word_table = (const float*)d_in[0];
    const float* char_table = (const float*)d_in[1];
    const float* conv_w     = (const float*)d_in[2];
    const float* conv_b     = (const float*)d_in[3];
    const float* w_ih_f     = (const float*)d_in[4];
    const float* w_hh_f     = (const float*)d_in[5];
    const float* b_f        = (const float*)d_in[6];
    const float* w_ih_r     = (const float*)d_in[7];
    const float* w_hh_r     = (const float*)d_in[8];
    const float* b_r        = (const float*)d_in[9];
    const float* lin_w      = (const float*)d_in[10];
    const float* lin_b      = (const float*)d_in[11];
    const float* start_t    = (const float*)d_in[12];
    const float* end_t      = (const float*)d_in[13];
    const float* trans      = (const float*)d_in[14];
    const int*   sent       = (const int*)d_in[15];
    const int*   word       = (const int*)d_in[16];
    const int*   tag        = (const int*)d_in[17];
    const void*  mask       = d_in[18];
    float* out = (float*)d_out;

    char* ws = (char*)d_ws;
    unsigned short* feat  = (unsigned short*)ws;                 // 8192*352*2   = 5,767,168 B
    unsigned short* wpack = (unsigned short*)(ws + 5767168);     // 2048*352*2   = 1,441,792 B
    unsigned short* gxb   = (unsigned short*)(ws + 5767168 + 1441792);           // 33,554,432 B
    float* hseq = (float*)(ws + 5767168 + 1441792 + 33554432);   // 16,777,216 B

    k_prep<<<dim3(6273), 256, 0, stream>>>(char_table, word, conv_w, conv_b,
                                           word_table, sent, w_ih_f, w_ih_r, out, feat, wpack);
    k_gemm<<<dim3(B_*S_/128, NG_/128), 256, 0, stream>>>(feat, wpack, b_f, b_r, gxb);
    k_lstm_all<<<dim3(64), 1024, 0, stream>>>(w_hh_f, w_hh_r, gxb, hseq);
    k_emcrf<<<dim3(B_), 256, 0, stream>>>(hseq, lin_w, lin_b, tag, mask, start_t, end_t, trans, out);
}

// Round 10
// 572.491 us; speedup vs baseline: 1.2974x; 1.2974x over previous
//
#include <hip/hip_runtime.h>
#include <math.h>

#define B_  64
#define S_  128
#define LW_ 20
#define CHAR_E_ 30
#define CHAR_C_ 30
#define WORD_E_ 300
#define H_  256
#define NC_ 25
#define F_  330
#define KP_ 352       // K padded to multiple of 32
#define G4_ 1024      // 4*H
#define NG_ 2048      // both directions' gates

typedef __attribute__((ext_vector_type(8))) short short8;
typedef __attribute__((ext_vector_type(4))) float floatx4;
typedef __attribute__((ext_vector_type(8))) int int8v;

__device__ __forceinline__ unsigned int f2bf(float f){
    unsigned int u = __float_as_uint(f);
    u += 0x7FFFu + ((u>>16)&1u);
    return (u>>16) & 0xFFFFu;
}
__device__ __forceinline__ float bf2f(unsigned int v){ return __uint_as_float(v<<16); }

// halfword g (0..3) of a uint2 holding 4 bf16 -> float (g literal -> pure shifts)
__device__ __forceinline__ float bfh(uint2 pk, int g){
    unsigned int w = (g < 2) ? pk.x : pk.y;
    return __uint_as_float((g & 1) ? (w & 0xffff0000u) : (w << 16));
}

// fast sigmoid/tanh: v_exp + v_rcp (single-instr trans ops) — verified numerics (R5/R8 pass)
__device__ __forceinline__ float sigf_(float x){ return __builtin_amdgcn_rcpf(1.0f+__expf(-x)); }
__device__ __forceinline__ float tanhf2_(float x){ return 1.0f - 2.0f*__builtin_amdgcn_rcpf(1.0f+__expf(2.0f*x)); }

// async global->LDS, 16B per lane; LDS dest is wave-uniform base + lane*16
__device__ __forceinline__ void gload16(const void* g, void* l){
    __builtin_amdgcn_global_load_lds((const __attribute__((address_space(1))) unsigned int*)g,
                                     (__attribute__((address_space(3))) unsigned int*)l, 16, 0, 0);
}

// LDS-only barrier: does NOT drain vmcnt, so global prefetch loads stay in flight.
#define BAR_LDS() __asm__ volatile("s_waitcnt lgkmcnt(0)\n\ts_barrier" ::: "memory")

// ---------------- merged prep: charconv | wemb | pack | init ----------------
__global__ __launch_bounds__(256) void k_prep(const float* ct, const int* word,
        const float* cw, const float* cb, const float* wt, const int* sent,
        const float* wf, const float* wr, float* out,
        unsigned short* feat, unsigned short* wpack){
    __shared__ __align__(16) float x[8][32][20];
    int blk = blockIdx.x;
    int tid = threadIdx.x;
    if(blk < 1024){
        int tok0 = blk*8;
        for(int e = tid; e < 8*32*20; e += 256){
            int t  = e % 20;
            int ic = (e/20) & 31;
            int tl = e / 640;
            int id = word[(size_t)(tok0+tl)*LW_ + t];
            float v = 0.f;
            if(ic < CHAR_E_ && id != 0) v = ct[(size_t)id*CHAR_E_ + ic];
            x[tl][ic][t] = v;
        }
        __syncthreads();
        if(tid < 240){
            int tl = tid/30, oc = tid%30;
            float acc[22];
            #pragma unroll
            for(int q=0;q<22;q++) acc[q] = 0.f;
            for(int ic=0; ic<CHAR_E_; ic++){
                float w0 = cw[(oc*CHAR_E_+ic)*3+0];
                float w1 = cw[(oc*CHAR_E_+ic)*3+1];
                float w2 = cw[(oc*CHAR_E_+ic)*3+2];
                const float* xr = &x[tl][ic][0];
                #pragma unroll
                for(int t4=0;t4<5;t4++){
                    float4 v = ((const float4*)xr)[t4];
                    int t0 = t4*4;
                    acc[t0+2] += v.x*w0; acc[t0+1] += v.x*w1; acc[t0+0] += v.x*w2;
                    acc[t0+3] += v.y*w0; acc[t0+2] += v.y*w1; acc[t0+1] += v.y*w2;
                    acc[t0+4] += v.z*w0; acc[t0+3] += v.z*w1; acc[t0+2] += v.z*w2;
                    acc[t0+5] += v.w*w0; acc[t0+4] += v.w*w1; acc[t0+3] += v.w*w2;
                }
            }
            float m = -1e30f;
            #pragma unroll
            for(int t=0;t<20;t++){ float v = acc[t+1]; m = fmaxf(m, v); }
            m += cb[oc];
            feat[(size_t)(tok0+tl)*KP_ + WORD_E_ + oc] = (unsigned short)f2bf(m);
        }
    } else if(blk < 1024+2432){
        int idx = (blk-1024)*256 + tid;
        int n = idx / 76, e4 = idx % 76;
        if(e4 < 75){
            float4 v = ((const float4*)(wt + (size_t)sent[n]*WORD_E_))[e4];
            unsigned int lo = f2bf(v.x) | (f2bf(v.y)<<16);
            unsigned int hi = f2bf(v.z) | (f2bf(v.w)<<16);
            uint2 pr; pr.x = lo; pr.y = hi;
            *(uint2*)(feat + (size_t)n*KP_ + e4*4) = pr;
        } else {
            unsigned int* z = (unsigned int*)(feat + (size_t)n*KP_ + 330);
            #pragma unroll
            for(int q=0;q<11;q++) z[q] = 0;
        }
    } else if(blk < 6272){
        int i = (blk-3456)*256 + tid;
        int r = i / KP_, k = i % KP_;
        const float* src = (r < G4_) ? wf : wr;
        int rr = r & (G4_-1);
        wpack[i] = (k < F_) ? (unsigned short)f2bf(src[(size_t)rr*F_ + k]) : 0;
    } else {
        if(tid == 0) *out = 0.f;
    }
}

// ---------------- bf16 MFMA GEMM: gx = feat(8192x352) . wpack(2048x352)^T + bias ----------------
// Output gxb layout matched to 16-wave LSTM consumer (R8-verified):
//   idx = (((dir*128+s)*32 + bgrp)*16 + w16)*128 + bb*64 + u*4 + g
__global__ __launch_bounds__(256) void k_gemm(const unsigned short* A, const unsigned short* Bw,
                                              const float* bf, const float* br, unsigned short* gxb){
    __shared__ __align__(16) unsigned short As[128*32];
    __shared__ __align__(16) unsigned short Bs[128*32];
    int m0 = blockIdx.x*128, n0 = blockIdx.y*128;
    int tid = threadIdx.x;
    int w = tid>>6, lane = tid&63, q = lane>>4, l16 = lane&15;
    int wr = w>>1, wc = w&1;
    int srow0 = w*32 + (lane>>2);
    int scol  = (lane&3)*8;
    floatx4 acc[4][4];
    #pragma unroll
    for(int i=0;i<4;i++)
        #pragma unroll
        for(int j=0;j<4;j++) acc[i][j] = (floatx4){0.f,0.f,0.f,0.f};

    for(int k0=0; k0<KP_; k0+=32){
        __syncthreads();
        gload16(A  + (size_t)(m0+srow0   )*KP_ + k0 + scol, (unsigned short*)As + w*1024      );
        gload16(A  + (size_t)(m0+srow0+16)*KP_ + k0 + scol, (unsigned short*)As + w*1024 + 512);
        gload16(Bw + (size_t)(n0+srow0   )*KP_ + k0 + scol, (unsigned short*)Bs + w*1024      );
        gload16(Bw + (size_t)(n0+srow0+16)*KP_ + k0 + scol, (unsigned short*)Bs + w*1024 + 512);
        __asm__ volatile("s_waitcnt vmcnt(0)" ::: "memory");
        __syncthreads();
        short8 a_[4], b_[4];
        #pragma unroll
        for(int i=0;i<4;i++) a_[i] = *(const short8*)&As[(wr*64 + i*16 + l16)*32 + q*8];
        #pragma unroll
        for(int j=0;j<4;j++) b_[j] = *(const short8*)&Bs[(wc*64 + j*16 + l16)*32 + q*8];
        #pragma unroll
        for(int i=0;i<4;i++)
            #pragma unroll
            for(int j=0;j<4;j++)
                acc[i][j] = __builtin_amdgcn_mfma_f32_16x16x32_bf16(a_[i], b_[j], acc[i][j], 0,0,0);
    }
    // epilogue: m = m0+wr*64+i*16+q*4+r (token), n = n0+wc*64+j*16+l16 (gate col)
    #pragma unroll
    for(int j=0;j<4;j++){
        int n = n0 + wc*64 + j*16 + l16;
        int dirr = n >> 10, grow = n & 1023;
        float bias = dirr ? br[grow] : bf[grow];
        int gg  = grow >> 8;
        int ug  = grow & 255;
        int w16 = ug >> 4, u = ug & 15;
        int ubase = w16*128 + u*4 + gg;
        #pragma unroll
        for(int i=0;i<4;i++){
            int mb = m0 + wr*64 + i*16 + q*4;
            #pragma unroll
            for(int r=0;r<4;r++){
                int m = mb + r;
                int b = m >> 7, s = m & 127;
                size_t idx = ((size_t)((dirr*128 + s)*32 + (b>>1)))*2048
                           + (size_t)(ubase + (b&1)*64);
                gxb[idx] = (unsigned short)f2bf(acc[i][j][r] + bias);
            }
        }
    }
}

// ---------------- one LSTM step: 16-unit wave, row-tile = gate (R8-verified) ----------------
// A rows: g*16 + u. D: col=l16 (batch), row=q*4+r (unit).
// Owning lanes l16<2 (8 lanes) scatter acc[g] b128 to wl[g*32 + l16*16 + q*4] (conflict-free);
// lanes<32 consume 1 cell each (bb=lane>>4, u=lane&15), conflict-free dword reads.
__device__ __forceinline__ void lstm_step16w(
    const unsigned char* hbb, unsigned char* hpub,
    float* wl, const int8v (*wreg)[2],
    int l16, int q, int lane,
    uint2 gg, float& cc, float* hs_ptr, const float inv_sc)
{
    floatx4 a[4];
    #pragma unroll
    for(int g=0; g<4; g++) a[g] = (floatx4){0.f,0.f,0.f,0.f};
    #pragma unroll
    for(int ki=0; ki<2; ki++){
        int8v hb = *(const int8v*)&hbb[l16*272 + ki*128 + q*32];
        #pragma unroll
        for(int g=0; g<4; g++)
            a[g] = __builtin_amdgcn_mfma_scale_f32_16x16x128_f8f6f4(wreg[g][ki], hb, a[g], 0,0,0,0x7F,0,0x7F);
    }
    if(l16 < 2){
        #pragma unroll
        for(int g=0; g<4; g++)
            *(floatx4*)&wl[g*32 + l16*16 + q*4] = a[g];
    }
    // same-wave DS in-order: write then read, no barrier (verified pattern)
    if(lane < 32){
        float iv = wl[0*32 + lane]*inv_sc + bfh(gg,0);
        float fv = wl[1*32 + lane]*inv_sc + bfh(gg,1);
        float gv = wl[2*32 + lane]*inv_sc + bfh(gg,2);
        float ov = wl[3*32 + lane]*inv_sc + bfh(gg,3);
        float cn = sigf_(fv)*cc + sigf_(iv)*tanhf2_(gv);
        cc = cn;
        float hv = sigf_(ov)*tanhf2_(cn);
        *hs_ptr = hv;
        unsigned int d8 = __builtin_amdgcn_cvt_pk_fp8_f32(hv*16.f, hv*16.f, 0u, false) & 0xFFu;
        *hpub = (unsigned char)d8;
    }
    BAR_LDS();   // h(t) published
}

// ---------------- persistent biLSTM: 64 blocks x 1024 threads (16 waves, 4/SIMD) ----------------
__global__ __launch_bounds__(1024,4) void k_lstm_all(const float* whhf, const float* whhr,
        const unsigned short* gxb, float* hseq)
{
    int bid = blockIdx.x;        // 0..63
    int dir = bid >> 5;
    int bgrp = bid & 31;         // batches bgrp*2, bgrp*2+1
    int tid = threadIdx.x;
    int w16  = tid >> 6;         // wave 0..15: units w16*16..w16*16+15
    int lane = tid & 63;
    int q    = lane >> 4;
    int l16  = lane & 15;
    int bb   = lane >> 4;        // (lane<32) cell batch 0..1
    int u    = lane & 15;        // (lane<32) cell unit-in-wave

    __shared__ __align__(16) unsigned char hlds[2][16*272];   // [buf][batchrow][unit] fp8 (rows 2..15 = 0)
    __shared__ __align__(16) float wregion[16*128];           // per-wave [g][2 batch][16 unit] f32

    const float* whh = dir ? whhr : whhf;

    // one-time: pack weight slice as K=128 fp8 A-fragments.
    int8v wreg[4][2];   // 64 VGPRs
    #pragma unroll
    for(int g=0; g<4; g++){
        const float* rp = whh + (size_t)(g*H_ + w16*16 + l16)*H_;
        #pragma unroll
        for(int ki=0; ki<2; ki++){
            const float* p = rp + ki*128 + q*32;
            int8v acc;
            #pragma unroll
            for(int wd=0; wd<8; wd++){
                unsigned int d = 0;
                d = __builtin_amdgcn_cvt_pk_fp8_f32(p[wd*4+0]*64.f, p[wd*4+1]*64.f, d, false);
                d = __builtin_amdgcn_cvt_pk_fp8_f32(p[wd*4+2]*64.f, p[wd*4+3]*64.f, d, true);
                acc[wd] = (int)d;
            }
            wreg[g][ki] = acc;
        }
    }

    for(int i = tid; i < 2*16*272/4; i += 1024) ((unsigned int*)hlds)[i] = 0;
    __syncthreads();

    const float inv_sc = 1.0f/1024.f;   // w x64, h x16
    float cc = 0.f;

    int s0 = dir ? (S_-1) : 0;
    // gates: idx = (((dir*128+s)*32 + bgrp)*16 + w16)*128 + lane*4 (uint2 = this cell's 4 gates)
    long gstep = dir ? -65536L : 65536L;
    const unsigned short* gp = gxb + ((size_t)((dir*128 + s0)*32 + bgrp))*2048 + w16*128 + lane*4;
    long hstep = dir ? -(long)(B_*H_) : (long)(B_*H_);
    float* hp = hseq + (((size_t)dir*S_ + s0)*B_ + bgrp*2 + bb)*H_ + w16*16 + u;

    float* wl = &wregion[w16*128];
    unsigned char* hpw0 = &hlds[0][bb*272 + w16*16 + u];
    unsigned char* hpw1 = &hlds[1][bb*272 + w16*16 + u];

    uint2 P = *(const uint2*)gp; gp += gstep;
    uint2 Q;

    for(int t=0; t<S_; t+=2){
        // prefetch step t+1's gates (in flight across step A)
        Q = *(const uint2*)gp; gp += gstep;
        lstm_step16w(&hlds[0][0], hpw1, wl, wreg, l16, q, lane, P, cc, hp, inv_sc);
        hp += hstep;
        // prefetch step t+2 (last iter lands 1 s-slot outside slice, inside gxb: harmless)
        P = *(const uint2*)gp; gp += gstep;
        lstm_step16w(&hlds[1][0], hpw0, wl, wreg, l16, q, lane, Q, cc, hp, inv_sc);
        hp += hstep;
    }
}

// ---------------- emissions: block = 8 (s,b) pairs, h staged in LDS ----------------
__global__ __launch_bounds__(256) void k_em(const float* hseq, const float* lw, const float* lb, float* em){
    __shared__ __align__(16) float hb[8][516];   // +4 pad
    int sb0 = blockIdx.x*8;
    int tid = threadIdx.x;
    for(int i = tid; i < 1024; i += 256){
        int p = i >> 7, r = i & 127;
        int sb = sb0 + p, s = sb >> 6, b = sb & 63;
        const float* src = (r < 64) ? (hseq + (((size_t)0*S_+s)*B_+b)*H_ + r*4)
                                    : (hseq + (((size_t)1*S_+s)*B_+b)*H_ + (r-64)*4);
        *(float4*)&hb[p][r*4] = *(const float4*)src;
    }
    __syncthreads();
    if(tid < 200){
        int p = tid / 25, nc = tid % 25;
        const float4* wv = (const float4*)(lw + (size_t)nc*2*H_);
        const float4* hv = (const float4*)&hb[p][0];
        float acc = lb[nc];
        #pragma unroll 16
        for(int k=0;k<128;k++){ float4 a=hv[k], ww=wv[k]; acc += a.x*ww.x + a.y*ww.y + a.z*ww.z + a.w*ww.w; }
        em[(size_t)(sb0+p)*NC_ + nc] = acc;
    }
}

// ---------------- CRF NLL: one block = one WAVE (64 threads) per batch, no barriers ----------------
__global__ void k_crf(const float* em, const int* tag, const void* mask,
                      const float* st, const float* et, const float* tr, float* out){
    __shared__ float trs[NC_*NC_];
    int b = blockIdx.x, tid = threadIdx.x;
    for(int i=tid;i<NC_*NC_;i+=64) trs[i]=tr[i];
    unsigned int first = *(const unsigned int*)mask;
    int ml;  // 0=int32, 1=uint8, 2=float32
    if(first == 1u) ml = 0;
    else if(first == 0x3F800000u) ml = 2;
    else ml = 1;
    __syncthreads();

    // gold path score
    float part = 0.f; int cnt = 0;
    for(int s = tid; s < S_; s += 64){
        float mkv;
        {
            int off = b*S_ + s;
            if(ml==0)      mkv = ((const int*)mask)[off] ? 1.f : 0.f;
            else if(ml==1) mkv = ((const unsigned char*)mask)[off] ? 1.f : 0.f;
            else           mkv = ((const float*)mask)[off];
        }
        cnt += (mkv != 0.f) ? 1 : 0;
        if(s == 0){
            int t0 = tag[b*S_];
            part += st[t0] + em[((size_t)0*B_ + b)*NC_ + t0];
        } else {
            int tp = tag[b*S_ + s-1], tc = tag[b*S_ + s];
            part += mkv * (trs[tp*NC_ + tc] + em[((size_t)s*B_ + b)*NC_ + tc]);
        }
    }
    for(int o=32;o>0;o>>=1){ part += __shfl_down(part, o); cnt += __shfl_down(cnt, o); }
    float score = 0.f;
    int len = __shfl(cnt, 0);
    float score0 = __shfl(part, 0);
    if(tid == 0) score = score0 + et[ tag[b*S_ + len-1] ];

    // E columns in registers
    float Ecol[NC_];
    if(tid < NC_){
        #pragma unroll
        for(int i=0;i<NC_;i++) Ecol[i] = __expf(trs[i*NC_+tid]);
    } else {
        #pragma unroll
        for(int i=0;i<NC_;i++) Ecol[i] = 0.f;
    }

    float alpha = (tid < NC_) ? (st[tid] + em[((size_t)0*B_ + b)*NC_ + tid]) : -1e30f;
    float em_n = (tid < NC_) ? em[((size_t)1*B_ + b)*NC_ + tid] : 0.f;

    for(int s=1;s<S_;s++){
        float em_c = em_n;
        if(s+1 < S_) em_n = (tid < NC_) ? em[((size_t)(s+1)*B_ + b)*NC_ + tid] : 0.f;
        float mkv;
        {
            int off = b*S_ + s;
            if(ml==0)      mkv = ((const int*)mask)[off] ? 1.f : 0.f;
            else if(ml==1) mkv = ((const unsigned char*)mask)[off] ? 1.f : 0.f;
            else           mkv = ((const float*)mask)[off];
        }
        float v = alpha;
        #pragma unroll
        for(int o=16;o>0;o>>=1) v = fmaxf(v, __shfl_down(v, o));
        float m = __shfl(v, 0);
        float a = (tid < NC_) ? __expf(alpha - m) : 0.f;
        float S0 = 0.f, S1 = 0.f;
        #pragma unroll
        for(int i=0;i<24;i+=2){ S0 += __shfl(a, i) * Ecol[i]; S1 += __shfl(a, i+1) * Ecol[i+1]; }
        S0 += __shfl(a, 24) * Ecol[24];
        float nxt = m + __logf(S0 + S1) + em_c;
        if(tid < NC_ && mkv != 0.f) alpha = nxt;
    }

    float v = (tid < NC_) ? (alpha + et[tid]) : -1e30f;
    float m2 = v;
    #pragma unroll
    for(int o=16;o>0;o>>=1) m2 = fmaxf(m2, __shfl_down(m2, o));
    m2 = __shfl(m2, 0);
    float e = (tid < NC_) ? __expf(v - m2) : 0.f;
    #pragma unroll
    for(int o=16;o>0;o>>=1) e += __shfl_down(e, o);
    if(tid == 0){
        float logZ = m2 + __logf(e);
        atomicAdd(out, logZ - score);
    }
}

extern "C" void kernel_launch(void* const* d_in, const int* in_sizes, int n_in,
                              void* d_out, int out_size, void* d_ws, size_t ws_size,
                              hipStream_t stream) {
    const float* word_table = (const float*)d_in[0];
    const float* char_table = (const float*)d_in[1];
    const float* conv_w     = (const float*)d_in[2];
    const float* conv_b     = (const float*)d_in[3];
    const float* w_ih_f     = (const float*)d_in[4];
    const float* w_hh_f     = (const float*)d_in[5];
    const float* b_f        = (const float*)d_in[6];
    const float* w_ih_r     = (const float*)d_in[7];
    const float* w_hh_r     = (const float*)d_in[8];
    const float* b_r        = (const float*)d_in[9];
    const float* lin_w      = (const float*)d_in[10];
    const float* lin_b      = (const float*)d_in[11];
    const float* start_t    = (const float*)d_in[12];
    const float* end_t      = (const float*)d_in[13];
    const float* trans      = (const float*)d_in[14];
    const int*   sent       = (const int*)d_in[15];
    const int*   word       = (const int*)d_in[16];
    const int*   tag        = (const int*)d_in[17];
    const void*  mask       = d_in[18];
    float* out = (float*)d_out;

    char* ws = (char*)d_ws;
    unsigned short* feat  = (unsigned short*)ws;                 // 8192*352*2   = 5,767,168 B
    unsigned short* wpack = (unsigned short*)(ws + 5767168);     // 2048*352*2   = 1,441,792 B
    unsigned short* gxb   = (unsigned short*)(ws + 5767168 + 1441792);           // 33,554,432 B
    float* hseq = (float*)(ws + 5767168 + 1441792 + 33554432);   // 16,777,216 B
    float* em   = (float*)(ws + 5767168 + 1441792 + 33554432 + 16777216);        // 204,800 f

    k_prep<<<dim3(6273), 256, 0, stream>>>(char_table, word, conv_w, conv_b,
                                           word_table, sent, w_ih_f, w_ih_r, out, feat, wpack);
    k_gemm<<<dim3(B_*S_/128, NG_/128), 256, 0, stream>>>(feat, wpack, b_f, b_r, gxb);
    k_lstm_all<<<dim3(64), 1024, 0, stream>>>(w_hh_f, w_hh_r, gxb, hseq);
    k_em<<<dim3(S_*B_/8), 256, 0, stream>>>(hseq, lin_w, lin_b, em);
    k_crf<<<dim3(B_), 64, 0, stream>>>(em, tag, mask, start_t, end_t, trans, out);
}

// Round 11
// 562.565 us; speedup vs baseline: 1.3203x; 1.0176x over previous
//
#include <hip/hip_runtime.h>
#include <math.h>

#define B_  64
#define S_  128
#define LW_ 20
#define CHAR_E_ 30
#define CHAR_C_ 30
#define WORD_E_ 300
#define H_  256
#define NC_ 25
#define F_  330
#define KP_ 352       // K padded to multiple of 32
#define G4_ 1024      // 4*H
#define NG_ 2048      // both directions' gates

typedef __attribute__((ext_vector_type(8))) short short8;
typedef __attribute__((ext_vector_type(4))) float floatx4;
typedef __attribute__((ext_vector_type(8))) int int8v;

__device__ __forceinline__ unsigned int f2bf(float f){
    unsigned int u = __float_as_uint(f);
    u += 0x7FFFu + ((u>>16)&1u);
    return (u>>16) & 0xFFFFu;
}
__device__ __forceinline__ float bf2f(unsigned int v){ return __uint_as_float(v<<16); }

// halfword g (0..3) of a uint2 holding 4 bf16 -> float (g literal -> pure shifts)
__device__ __forceinline__ float bfh(uint2 pk, int g){
    unsigned int w = (g < 2) ? pk.x : pk.y;
    return __uint_as_float((g & 1) ? (w & 0xffff0000u) : (w << 16));
}

// fast sigmoid/tanh: v_exp + v_rcp (single-instr trans ops) — verified numerics (R5/R8 pass)
__device__ __forceinline__ float sigf_(float x){ return __builtin_amdgcn_rcpf(1.0f+__expf(-x)); }
__device__ __forceinline__ float tanhf2_(float x){ return 1.0f - 2.0f*__builtin_amdgcn_rcpf(1.0f+__expf(2.0f*x)); }

// async global->LDS, 16B per lane; LDS dest is wave-uniform base + lane*16
__device__ __forceinline__ void gload16(const void* g, void* l){
    __builtin_amdgcn_global_load_lds((const __attribute__((address_space(1))) unsigned int*)g,
                                     (__attribute__((address_space(3))) unsigned int*)l, 16, 0, 0);
}

// LDS-only barrier: does NOT drain vmcnt, so global prefetch loads stay in flight.
#define BAR_LDS() __asm__ volatile("s_waitcnt lgkmcnt(0)\n\ts_barrier" ::: "memory")

// ---------------- merged prep: charconv | wemb | pack | init ----------------
__global__ __launch_bounds__(256) void k_prep(const float* ct, const int* word,
        const float* cw, const float* cb, const float* wt, const int* sent,
        const float* wf, const float* wr, float* out,
        unsigned short* feat, unsigned short* wpack){
    __shared__ __align__(16) float x[8][32][20];
    int blk = blockIdx.x;
    int tid = threadIdx.x;
    if(blk < 1024){
        int tok0 = blk*8;
        for(int e = tid; e < 8*32*20; e += 256){
            int t  = e % 20;
            int ic = (e/20) & 31;
            int tl = e / 640;
            int id = word[(size_t)(tok0+tl)*LW_ + t];
            float v = 0.f;
            if(ic < CHAR_E_ && id != 0) v = ct[(size_t)id*CHAR_E_ + ic];
            x[tl][ic][t] = v;
        }
        __syncthreads();
        if(tid < 240){
            int tl = tid/30, oc = tid%30;
            float acc[22];
            #pragma unroll
            for(int q=0;q<22;q++) acc[q] = 0.f;
            for(int ic=0; ic<CHAR_E_; ic++){
                float w0 = cw[(oc*CHAR_E_+ic)*3+0];
                float w1 = cw[(oc*CHAR_E_+ic)*3+1];
                float w2 = cw[(oc*CHAR_E_+ic)*3+2];
                const float* xr = &x[tl][ic][0];
                #pragma unroll
                for(int t4=0;t4<5;t4++){
                    float4 v = ((const float4*)xr)[t4];
                    int t0 = t4*4;
                    acc[t0+2] += v.x*w0; acc[t0+1] += v.x*w1; acc[t0+0] += v.x*w2;
                    acc[t0+3] += v.y*w0; acc[t0+2] += v.y*w1; acc[t0+1] += v.y*w2;
                    acc[t0+4] += v.z*w0; acc[t0+3] += v.z*w1; acc[t0+2] += v.z*w2;
                    acc[t0+5] += v.w*w0; acc[t0+4] += v.w*w1; acc[t0+3] += v.w*w2;
                }
            }
            float m = -1e30f;
            #pragma unroll
            for(int t=0;t<20;t++){ float v = acc[t+1]; m = fmaxf(m, v); }
            m += cb[oc];
            feat[(size_t)(tok0+tl)*KP_ + WORD_E_ + oc] = (unsigned short)f2bf(m);
        }
    } else if(blk < 1024+2432){
        int idx = (blk-1024)*256 + tid;
        int n = idx / 76, e4 = idx % 76;
        if(e4 < 75){
            float4 v = ((const float4*)(wt + (size_t)sent[n]*WORD_E_))[e4];
            unsigned int lo = f2bf(v.x) | (f2bf(v.y)<<16);
            unsigned int hi = f2bf(v.z) | (f2bf(v.w)<<16);
            uint2 pr; pr.x = lo; pr.y = hi;
            *(uint2*)(feat + (size_t)n*KP_ + e4*4) = pr;
        } else {
            unsigned int* z = (unsigned int*)(feat + (size_t)n*KP_ + 330);
            #pragma unroll
            for(int q=0;q<11;q++) z[q] = 0;
        }
    } else if(blk < 6272){
        int i = (blk-3456)*256 + tid;
        int r = i / KP_, k = i % KP_;
        const float* src = (r < G4_) ? wf : wr;
        int rr = r & (G4_-1);
        wpack[i] = (k < F_) ? (unsigned short)f2bf(src[(size_t)rr*F_ + k]) : 0;
    } else {
        if(tid == 0) *out = 0.f;
    }
}

// ---------------- bf16 MFMA GEMM: gx = feat(8192x352) . wpack(2048x352)^T + bias ----------------
// Output gxb layout matched to 16-wave LSTM consumer (R8-verified):
//   idx = (((dir*128+s)*32 + bgrp)*16 + w16)*128 + bb*64 + u*4 + g
__global__ __launch_bounds__(256) void k_gemm(const unsigned short* A, const unsigned short* Bw,
                                              const float* bf, const float* br, unsigned short* gxb){
    __shared__ __align__(16) unsigned short As[128*32];
    __shared__ __align__(16) unsigned short Bs[128*32];
    int m0 = blockIdx.x*128, n0 = blockIdx.y*128;
    int tid = threadIdx.x;
    int w = tid>>6, lane = tid&63, q = lane>>4, l16 = lane&15;
    int wr = w>>1, wc = w&1;
    int srow0 = w*32 + (lane>>2);
    int scol  = (lane&3)*8;
    floatx4 acc[4][4];
    #pragma unroll
    for(int i=0;i<4;i++)
        #pragma unroll
        for(int j=0;j<4;j++) acc[i][j] = (floatx4){0.f,0.f,0.f,0.f};

    for(int k0=0; k0<KP_; k0+=32){
        __syncthreads();
        gload16(A  + (size_t)(m0+srow0   )*KP_ + k0 + scol, (unsigned short*)As + w*1024      );
        gload16(A  + (size_t)(m0+srow0+16)*KP_ + k0 + scol, (unsigned short*)As + w*1024 + 512);
        gload16(Bw + (size_t)(n0+srow0   )*KP_ + k0 + scol, (unsigned short*)Bs + w*1024      );
        gload16(Bw + (size_t)(n0+srow0+16)*KP_ + k0 + scol, (unsigned short*)Bs + w*1024 + 512);
        __asm__ volatile("s_waitcnt vmcnt(0)" ::: "memory");
        __syncthreads();
        short8 a_[4], b_[4];
        #pragma unroll
        for(int i=0;i<4;i++) a_[i] = *(const short8*)&As[(wr*64 + i*16 + l16)*32 + q*8];
        #pragma unroll
        for(int j=0;j<4;j++) b_[j] = *(const short8*)&Bs[(wc*64 + j*16 + l16)*32 + q*8];
        #pragma unroll
        for(int i=0;i<4;i++)
            #pragma unroll
            for(int j=0;j<4;j++)
                acc[i][j] = __builtin_amdgcn_mfma_f32_16x16x32_bf16(a_[i], b_[j], acc[i][j], 0,0,0);
    }
    // epilogue: m = m0+wr*64+i*16+q*4+r (token), n = n0+wc*64+j*16+l16 (gate col)
    #pragma unroll
    for(int j=0;j<4;j++){
        int n = n0 + wc*64 + j*16 + l16;
        int dirr = n >> 10, grow = n & 1023;
        float bias = dirr ? br[grow] : bf[grow];
        int gg  = grow >> 8;
        int ug  = grow & 255;
        int w16 = ug >> 4, u = ug & 15;
        int ubase = w16*128 + u*4 + gg;
        #pragma unroll
        for(int i=0;i<4;i++){
            int mb = m0 + wr*64 + i*16 + q*4;
            #pragma unroll
            for(int r=0;r<4;r++){
                int m = mb + r;
                int b = m >> 7, s = m & 127;
                size_t idx = ((size_t)((dirr*128 + s)*32 + (b>>1)))*2048
                           + (size_t)(ubase + (b&1)*64);
                gxb[idx] = (unsigned short)f2bf(acc[i][j][r] + bias);
            }
        }
    }
}

// ---------------- one LSTM step: 16-unit wave, row-tile = gate (R8-verified) ----------------
__device__ __forceinline__ void lstm_step16w(
    const unsigned char* hbb, unsigned char* hpub,
    float* wl, const int8v (*wreg)[2],
    int l16, int q, int lane,
    uint2 gg, float& cc, float* hs_ptr, const float inv_sc)
{
    floatx4 a[4];
    #pragma unroll
    for(int g=0; g<4; g++) a[g] = (floatx4){0.f,0.f,0.f,0.f};
    #pragma unroll
    for(int ki=0; ki<2; ki++){
        int8v hb = *(const int8v*)&hbb[l16*272 + ki*128 + q*32];
        #pragma unroll
        for(int g=0; g<4; g++)
            a[g] = __builtin_amdgcn_mfma_scale_f32_16x16x128_f8f6f4(wreg[g][ki], hb, a[g], 0,0,0,0x7F,0,0x7F);
    }
    if(l16 < 2){
        #pragma unroll
        for(int g=0; g<4; g++)
            *(floatx4*)&wl[g*32 + l16*16 + q*4] = a[g];
    }
    // same-wave DS in-order: write then read, no barrier (verified pattern)
    if(lane < 32){
        float iv = wl[0*32 + lane]*inv_sc + bfh(gg,0);
        float fv = wl[1*32 + lane]*inv_sc + bfh(gg,1);
        float gv = wl[2*32 + lane]*inv_sc + bfh(gg,2);
        float ov = wl[3*32 + lane]*inv_sc + bfh(gg,3);
        float cn = sigf_(fv)*cc + sigf_(iv)*tanhf2_(gv);
        cc = cn;
        float hv = sigf_(ov)*tanhf2_(cn);
        *hs_ptr = hv;
        unsigned int d8 = __builtin_amdgcn_cvt_pk_fp8_f32(hv*16.f, hv*16.f, 0u, false) & 0xFFu;
        *hpub = (unsigned char)d8;
    }
    BAR_LDS();   // h(t) published
}

// ---------------- persistent biLSTM: 64 blocks x 1024 threads (16 waves, 4/SIMD) ----------------
// NEW (R11): asymmetric wave priority breaks the per-step phase lockstep — half the waves on
// each SIMD (under either round-robin or chunked wave->SIMD mapping) run at prio 1, complete
// their MFMA block first, and overlap their VALU/LDS phase with the other half's MFMAs.
__global__ __launch_bounds__(1024,4) void k_lstm_all(const float* whhf, const float* whhr,
        const unsigned short* gxb, float* hseq)
{
    int bid = blockIdx.x;        // 0..63
    int dir = bid >> 5;
    int bgrp = bid & 31;         // batches bgrp*2, bgrp*2+1
    int tid = threadIdx.x;
    int w16  = tid >> 6;         // wave 0..15: units w16*16..w16*16+15
    int lane = tid & 63;
    int q    = lane >> 4;
    int l16  = lane & 15;
    int bb   = lane >> 4;        // (lane<32) cell batch 0..1
    int u    = lane & 15;        // (lane<32) cell unit-in-wave

    __shared__ __align__(16) unsigned char hlds[2][16*272];   // [buf][batchrow][unit] fp8 (rows 2..15 = 0)
    __shared__ __align__(16) float wregion[16*128];           // per-wave [g][2 batch][16 unit] f32

    const float* whh = dir ? whhr : whhf;

    // one-time: pack weight slice as K=128 fp8 A-fragments.
    int8v wreg[4][2];   // 64 VGPRs
    #pragma unroll
    for(int g=0; g<4; g++){
        const float* rp = whh + (size_t)(g*H_ + w16*16 + l16)*H_;
        #pragma unroll
        for(int ki=0; ki<2; ki++){
            const float* p = rp + ki*128 + q*32;
            int8v acc;
            #pragma unroll
            for(int wd=0; wd<8; wd++){
                unsigned int d = 0;
                d = __builtin_amdgcn_cvt_pk_fp8_f32(p[wd*4+0]*64.f, p[wd*4+1]*64.f, d, false);
                d = __builtin_amdgcn_cvt_pk_fp8_f32(p[wd*4+2]*64.f, p[wd*4+3]*64.f, d, true);
                acc[wd] = (int)d;
            }
            wreg[g][ki] = acc;
        }
    }

    for(int i = tid; i < 2*16*272/4; i += 1024) ((unsigned int*)hlds)[i] = 0;
    __syncthreads();

    // phase-stagger: alternate priority within each SIMD under round-robin OR chunked mapping
    if(((w16 ^ (w16 >> 2)) & 1)) __builtin_amdgcn_s_setprio(1);

    const float inv_sc = 1.0f/1024.f;   // w x64, h x16
    float cc = 0.f;

    int s0 = dir ? (S_-1) : 0;
    // gates: idx = (((dir*128+s)*32 + bgrp)*16 + w16)*128 + lane*4 (uint2 = this cell's 4 gates)
    long gstep = dir ? -65536L : 65536L;
    const unsigned short* gp = gxb + ((size_t)((dir*128 + s0)*32 + bgrp))*2048 + w16*128 + lane*4;
    long hstep = dir ? -(long)(B_*H_) : (long)(B_*H_);
    float* hp = hseq + (((size_t)dir*S_ + s0)*B_ + bgrp*2 + bb)*H_ + w16*16 + u;

    float* wl = &wregion[w16*128];
    unsigned char* hpw0 = &hlds[0][bb*272 + w16*16 + u];
    unsigned char* hpw1 = &hlds[1][bb*272 + w16*16 + u];

    uint2 P = *(const uint2*)gp; gp += gstep;
    uint2 Q;

    for(int t=0; t<S_; t+=2){
        // prefetch step t+1's gates (in flight across step A)
        Q = *(const uint2*)gp; gp += gstep;
        lstm_step16w(&hlds[0][0], hpw1, wl, wreg, l16, q, lane, P, cc, hp, inv_sc);
        hp += hstep;
        // prefetch step t+2 (last iter lands 1 s-slot outside slice, inside gxb: harmless)
        P = *(const uint2*)gp; gp += gstep;
        lstm_step16w(&hlds[1][0], hpw0, wl, wreg, l16, q, lane, Q, cc, hp, inv_sc);
        hp += hstep;
    }
}

// ---------------- emissions: block = 8 (s,b) pairs, h staged in LDS ----------------
__global__ __launch_bounds__(256) void k_em(const float* hseq, const float* lw, const float* lb, float* em){
    __shared__ __align__(16) float hb[8][516];   // +4 pad
    int sb0 = blockIdx.x*8;
    int tid = threadIdx.x;
    for(int i = tid; i < 1024; i += 256){
        int p = i >> 7, r = i & 127;
        int sb = sb0 + p, s = sb >> 6, b = sb & 63;
        const float* src = (r < 64) ? (hseq + (((size_t)0*S_+s)*B_+b)*H_ + r*4)
                                    : (hseq + (((size_t)1*S_+s)*B_+b)*H_ + (r-64)*4);
        *(float4*)&hb[p][r*4] = *(const float4*)src;
    }
    __syncthreads();
    if(tid < 200){
        int p = tid / 25, nc = tid % 25;
        const float4* wv = (const float4*)(lw + (size_t)nc*2*H_);
        const float4* hv = (const float4*)&hb[p][0];
        float acc = lb[nc];
        #pragma unroll 16
        for(int k=0;k<128;k++){ float4 a=hv[k], ww=wv[k]; acc += a.x*ww.x + a.y*ww.y + a.z*ww.z + a.w*ww.w; }
        em[(size_t)(sb0+p)*NC_ + nc] = acc;
    }
}

// ---------------- CRF NLL: one block = one WAVE (64 threads) per batch, no barriers ----------------
__global__ void k_crf(const float* em, const int* tag, const void* mask,
                      const float* st, const float* et, const float* tr, float* out){
    __shared__ float trs[NC_*NC_];
    int b = blockIdx.x, tid = threadIdx.x;
    for(int i=tid;i<NC_*NC_;i+=64) trs[i]=tr[i];
    unsigned int first = *(const unsigned int*)mask;
    int ml;  // 0=int32, 1=uint8, 2=float32
    if(first == 1u) ml = 0;
    else if(first == 0x3F800000u) ml = 2;
    else ml = 1;
    __syncthreads();

    // gold path score
    float part = 0.f; int cnt = 0;
    for(int s = tid; s < S_; s += 64){
        float mkv;
        {
            int off = b*S_ + s;
            if(ml==0)      mkv = ((const int*)mask)[off] ? 1.f : 0.f;
            else if(ml==1) mkv = ((const unsigned char*)mask)[off] ? 1.f : 0.f;
            else           mkv = ((const float*)mask)[off];
        }
        cnt += (mkv != 0.f) ? 1 : 0;
        if(s == 0){
            int t0 = tag[b*S_];
            part += st[t0] + em[((size_t)0*B_ + b)*NC_ + t0];
        } else {
            int tp = tag[b*S_ + s-1], tc = tag[b*S_ + s];
            part += mkv * (trs[tp*NC_ + tc] + em[((size_t)s*B_ + b)*NC_ + tc]);
        }
    }
    for(int o=32;o>0;o>>=1){ part += __shfl_down(part, o); cnt += __shfl_down(cnt, o); }
    float score = 0.f;
    int len = __shfl(cnt, 0);
    float score0 = __shfl(part, 0);
    if(tid == 0) score = score0 + et[ tag[b*S_ + len-1] ];

    // E columns in registers
    float Ecol[NC_];
    if(tid < NC_){
        #pragma unroll
        for(int i=0;i<NC_;i++) Ecol[i] = __expf(trs[i*NC_+tid]);
    } else {
        #pragma unroll
        for(int i=0;i<NC_;i++) Ecol[i] = 0.f;
    }

    float alpha = (tid < NC_) ? (st[tid] + em[((size_t)0*B_ + b)*NC_ + tid]) : -1e30f;
    float em_n = (tid < NC_) ? em[((size_t)1*B_ + b)*NC_ + tid] : 0.f;

    for(int s=1;s<S_;s++){
        float em_c = em_n;
        if(s+1 < S_) em_n = (tid < NC_) ? em[((size_t)(s+1)*B_ + b)*NC_ + tid] : 0.f;
        float mkv;
        {
            int off = b*S_ + s;
            if(ml==0)      mkv = ((const int*)mask)[off] ? 1.f : 0.f;
            else if(ml==1) mkv = ((const unsigned char*)mask)[off] ? 1.f : 0.f;
            else           mkv = ((const float*)mask)[off];
        }
        float v = alpha;
        #pragma unroll
        for(int o=16;o>0;o>>=1) v = fmaxf(v, __shfl_down(v, o));
        float m = __shfl(v, 0);
        float a = (tid < NC_) ? __expf(alpha - m) : 0.f;
        float S0 = 0.f, S1 = 0.f;
        #pragma unroll
        for(int i=0;i<24;i+=2){ S0 += __shfl(a, i) * Ecol[i]; S1 += __shfl(a, i+1) * Ecol[i+1]; }
        S0 += __shfl(a, 24) * Ecol[24];
        float nxt = m + __logf(S0 + S1) + em_c;
        if(tid < NC_ && mkv != 0.f) alpha = nxt;
    }

    float v = (tid < NC_) ? (alpha + et[tid]) : -1e30f;
    float m2 = v;
    #pragma unroll
    for(int o=16;o>0;o>>=1) m2 = fmaxf(m2, __shfl_down(m2, o));
    m2 = __shfl(m2, 0);
    float e = (tid < NC_) ? __expf(v - m2) : 0.f;
    #pragma unroll
    for(int o=16;o>0;o>>=1) e += __shfl_down(e, o);
    if(tid == 0){
        float logZ = m2 + __logf(e);
        atomicAdd(out, logZ - score);
    }
}

extern "C" void kernel_launch(void* const* d_in, const int* in_sizes, int n_in,
                              void* d_out, int out_size, void* d_ws, size_t ws_size,
                              hipStream_t stream) {
    const float* word_table = (const float*)d_in[0];
    const float* char_table = (const float*)d_in[1];
    const float* conv_w     = (const float*)d_in[2];
    const float* conv_b     = (const float*)d_in[3];
    const float* w_ih_f     = (const float*)d_in[4];
    const float* w_hh_f     = (const float*)d_in[5];
    const float* b_f        = (const float*)d_in[6];
    const float* w_ih_r     = (const float*)d_in[7];
    const float* w_hh_r     = (const float*)d_in[8];
    const float* b_r        = (const float*)d_in[9];
    const float* lin_w      = (const float*)d_in[10];
    const float* lin_b      = (const float*)d_in[11];
    const float* start_t    = (const float*)d_in[12];
    const float* end_t      = (const float*)d_in[13];
    const float* trans      = (const float*)d_in[14];
    const int*   sent       = (const int*)d_in[15];
    const int*   word       = (const int*)d_in[16];
    const int*   tag        = (const int*)d_in[17];
    const void*  mask       = d_in[18];
    float* out = (float*)d_out;

    char* ws = (char*)d_ws;
    unsigned short* feat  = (unsigned short*)ws;                 // 8192*352*2   = 5,767,168 B
    unsigned short* wpack = (unsigned short*)(ws + 5767168);     // 2048*352*2   = 1,441,792 B
    unsigned short* gxb   = (unsigned short*)(ws + 5767168 + 1441792);           // 33,554,432 B
    float* hseq = (float*)(ws + 5767168 + 1441792 + 33554432);   // 16,777,216 B
    float* em   = (float*)(ws + 5767168 + 1441792 + 33554432 + 16777216);        // 204,800 f

    k_prep<<<dim3(6273), 256, 0, stream>>>(char_table, word, conv_w, conv_b,
                                           word_table, sent, w_ih_f, w_ih_r, out, feat, wpack);
    k_gemm<<<dim3(B_*S_/128, NG_/128), 256, 0, stream>>>(feat, wpack, b_f, b_r, gxb);
    k_lstm_all<<<dim3(64), 1024, 0, stream>>>(w_hh_f, w_hh_r, gxb, hseq);
    k_em<<<dim3(S_*B_/8), 256, 0, stream>>>(hseq, lin_w, lin_b, em);
    k_crf<<<dim3(B_), 64, 0, stream>>>(em, tag, mask, start_t, end_t, trans, out);
}

// Round 17
// 537.390 us; speedup vs baseline: 1.3822x; 1.0468x over previous
//
#include <hip/hip_runtime.h>
#include <math.h>

#define B_  64
#define S_  128
#define LW_ 20
#define CHAR_E_ 30
#define CHAR_C_ 30
#define WORD_E_ 300
#define H_  256
#define NC_ 25
#define F_  330
#define KP_ 352       // K padded to multiple of 32
#define G4_ 1024      // 4*H
#define NG_ 2048      // both directions' gates

typedef __attribute__((ext_vector_type(8))) short short8;
typedef __attribute__((ext_vector_type(4))) float floatx4;
typedef __attribute__((ext_vector_type(8))) int int8v;

__device__ __forceinline__ unsigned int f2bf(float f){
    unsigned int u = __float_as_uint(f);
    u += 0x7FFFu + ((u>>16)&1u);
    return (u>>16) & 0xFFFFu;
}
__device__ __forceinline__ float bf2f(unsigned int v){ return __uint_as_float(v<<16); }

// halfword g (0..3) of a uint2 holding 4 bf16 -> float (g literal -> pure shifts)
__device__ __forceinline__ float bfh(uint2 pk, int g){
    unsigned int w = (g < 2) ? pk.x : pk.y;
    return __uint_as_float((g & 1) ? (w & 0xffff0000u) : (w << 16));
}

// fast sigmoid/tanh: v_exp + v_rcp (single-instr trans ops) — verified numerics (R5/R8 pass)
__device__ __forceinline__ float sigf_(float x){ return __builtin_amdgcn_rcpf(1.0f+__expf(-x)); }
__device__ __forceinline__ float tanhf2_(float x){ return 1.0f - 2.0f*__builtin_amdgcn_rcpf(1.0f+__expf(2.0f*x)); }

// async global->LDS, 16B per lane; LDS dest is wave-uniform base + lane*16
__device__ __forceinline__ void gload16(const void* g, void* l){
    __builtin_amdgcn_global_load_lds((const __attribute__((address_space(1))) unsigned int*)g,
                                     (__attribute__((address_space(3))) unsigned int*)l, 16, 0, 0);
}

// LDS-only barrier: does NOT drain vmcnt, so global prefetch loads stay in flight.
#define BAR_LDS() __asm__ volatile("s_waitcnt lgkmcnt(0)\n\ts_barrier" ::: "memory")

// ---------------- merged prep: charconv | wemb | pack | init ----------------
__global__ __launch_bounds__(256) void k_prep(const float* ct, const int* word,
        const float* cw, const float* cb, const float* wt, const int* sent,
        const float* wf, const float* wr, float* out,
        unsigned short* feat, unsigned short* wpack){
    __shared__ __align__(16) float x[8][32][20];
    int blk = blockIdx.x;
    int tid = threadIdx.x;
    if(blk < 1024){
        int tok0 = blk*8;
        for(int e = tid; e < 8*32*20; e += 256){
            int t  = e % 20;
            int ic = (e/20) & 31;
            int tl = e / 640;
            int id = word[(size_t)(tok0+tl)*LW_ + t];
            float v = 0.f;
            if(ic < CHAR_E_ && id != 0) v = ct[(size_t)id*CHAR_E_ + ic];
            x[tl][ic][t] = v;
        }
        __syncthreads();
        if(tid < 240){
            int tl = tid/30, oc = tid%30;
            float acc[22];
            #pragma unroll
            for(int q=0;q<22;q++) acc[q] = 0.f;
            for(int ic=0; ic<CHAR_E_; ic++){
                float w0 = cw[(oc*CHAR_E_+ic)*3+0];
                float w1 = cw[(oc*CHAR_E_+ic)*3+1];
                float w2 = cw[(oc*CHAR_E_+ic)*3+2];
                const float* xr = &x[tl][ic][0];
                #pragma unroll
                for(int t4=0;t4<5;t4++){
                    float4 v = ((const float4*)xr)[t4];
                    int t0 = t4*4;
                    acc[t0+2] += v.x*w0; acc[t0+1] += v.x*w1; acc[t0+0] += v.x*w2;
                    acc[t0+3] += v.y*w0; acc[t0+2] += v.y*w1; acc[t0+1] += v.y*w2;
                    acc[t0+4] += v.z*w0; acc[t0+3] += v.z*w1; acc[t0+2] += v.z*w2;
                    acc[t0+5] += v.w*w0; acc[t0+4] += v.w*w1; acc[t0+3] += v.w*w2;
                }
            }
            float m = -1e30f;
            #pragma unroll
            for(int t=0;t<20;t++){ float v = acc[t+1]; m = fmaxf(m, v); }
            m += cb[oc];
            feat[(size_t)(tok0+tl)*KP_ + WORD_E_ + oc] = (unsigned short)f2bf(m);
        }
    } else if(blk < 1024+2432){
        int idx = (blk-1024)*256 + tid;
        int n = idx / 76, e4 = idx % 76;
        if(e4 < 75){
            float4 v = ((const float4*)(wt + (size_t)sent[n]*WORD_E_))[e4];
            unsigned int lo = f2bf(v.x) | (f2bf(v.y)<<16);
            unsigned int hi = f2bf(v.z) | (f2bf(v.w)<<16);
            uint2 pr; pr.x = lo; pr.y = hi;
            *(uint2*)(feat + (size_t)n*KP_ + e4*4) = pr;
        } else {
            unsigned int* z = (unsigned int*)(feat + (size_t)n*KP_ + 330);
            #pragma unroll
            for(int q=0;q<11;q++) z[q] = 0;
        }
    } else if(blk < 6272){
        int i = (blk-3456)*256 + tid;
        int r = i / KP_, k = i % KP_;
        const float* src = (r < G4_) ? wf : wr;
        int rr = r & (G4_-1);
        wpack[i] = (k < F_) ? (unsigned short)f2bf(src[(size_t)rr*F_ + k]) : 0;
    } else {
        if(tid == 0) *out = 0.f;
    }
}

// ---------------- bf16 MFMA GEMM: gx = feat(8192x352) . wpack(2048x352)^T + bias ----------------
// Output gxb layout matched to 16-wave LSTM consumer (R8-verified):
//   idx = (((dir*128+s)*32 + bgrp)*16 + w16)*128 + bb*64 + u*4 + g
__global__ __launch_bounds__(256) void k_gemm(const unsigned short* A, const unsigned short* Bw,
                                              const float* bf, const float* br, unsigned short* gxb){
    __shared__ __align__(16) unsigned short As[128*32];
    __shared__ __align__(16) unsigned short Bs[128*32];
    int m0 = blockIdx.x*128, n0 = blockIdx.y*128;
    int tid = threadIdx.x;
    int w = tid>>6, lane = tid&63, q = lane>>4, l16 = lane&15;
    int wr = w>>1, wc = w&1;
    int srow0 = w*32 + (lane>>2);
    int scol  = (lane&3)*8;
    floatx4 acc[4][4];
    #pragma unroll
    for(int i=0;i<4;i++)
        #pragma unroll
        for(int j=0;j<4;j++) acc[i][j] = (floatx4){0.f,0.f,0.f,0.f};

    for(int k0=0; k0<KP_; k0+=32){
        __syncthreads();
        gload16(A  + (size_t)(m0+srow0   )*KP_ + k0 + scol, (unsigned short*)As + w*1024      );
        gload16(A  + (size_t)(m0+srow0+16)*KP_ + k0 + scol, (unsigned short*)As + w*1024 + 512);
        gload16(Bw + (size_t)(n0+srow0   )*KP_ + k0 + scol, (unsigned short*)Bs + w*1024      );
        gload16(Bw + (size_t)(n0+srow0+16)*KP_ + k0 + scol, (unsigned short*)Bs + w*1024 + 512);
        __asm__ volatile("s_waitcnt vmcnt(0)" ::: "memory");
        __syncthreads();
        short8 a_[4], b_[4];
        #pragma unroll
        for(int i=0;i<4;i++) a_[i] = *(const short8*)&As[(wr*64 + i*16 + l16)*32 + q*8];
        #pragma unroll
        for(int j=0;j<4;j++) b_[j] = *(const short8*)&Bs[(wc*64 + j*16 + l16)*32 + q*8];
        #pragma unroll
        for(int i=0;i<4;i++)
            #pragma unroll
            for(int j=0;j<4;j++)
                acc[i][j] = __builtin_amdgcn_mfma_f32_16x16x32_bf16(a_[i], b_[j], acc[i][j], 0,0,0);
    }
    // epilogue: m = m0+wr*64+i*16+q*4+r (token), n = n0+wc*64+j*16+l16 (gate col)
    #pragma unroll
    for(int j=0;j<4;j++){
        int n = n0 + wc*64 + j*16 + l16;
        int dirr = n >> 10, grow = n & 1023;
        float bias = dirr ? br[grow] : bf[grow];
        int gg  = grow >> 8;
        int ug  = grow & 255;
        int w16 = ug >> 4, u = ug & 15;
        int ubase = w16*128 + u*4 + gg;
        #pragma unroll
        for(int i=0;i<4;i++){
            int mb = m0 + wr*64 + i*16 + q*4;
            #pragma unroll
            for(int r=0;r<4;r++){
                int m = mb + r;
                int b = m >> 7, s = m & 127;
                size_t idx = ((size_t)((dirr*128 + s)*32 + (b>>1)))*2048
                           + (size_t)(ubase + (b&1)*64);
                gxb[idx] = (unsigned short)f2bf(acc[i][j][r] + bias);
            }
        }
    }
}

// ---------------- one LSTM step: OPERAND-SWAPPED MFMA — zero gate redistribution ----------------
// D = h x W^T: row = batch (published at hlds row 4b -> D row 4b = lane q=b, reg 0),
// col = l16 = unit. So cell (batch bb, unit u) lands in reg 0 of lane bb*16+u — the
// consumer lane itself. No LDS round-trip; MFMA output feeds VALU directly.
__device__ __forceinline__ void lstm_step16w(
    const unsigned char* hbb, unsigned char* hpub,
    const int8v (*wreg)[2],
    int l16, int q, int lane,
    uint2 gg, float& cc, float* hs_ptr, const float inv_sc)
{
    floatx4 a[4];
    #pragma unroll
    for(int g=0; g<4; g++) a[g] = (floatx4){0.f,0.f,0.f,0.f};
    #pragma unroll
    for(int ki=0; ki<2; ki++){
        int8v hb = *(const int8v*)&hbb[l16*272 + ki*128 + q*32];   // A-frag: row=l16, k=ki*128+q*32
        #pragma unroll
        for(int g=0; g<4; g++)
            a[g] = __builtin_amdgcn_mfma_scale_f32_16x16x128_f8f6f4(hb, wreg[g][ki], a[g], 0,0,0,0x7F,0,0x7F);
    }
    // consumer lane (bb=lane>>4, u=lane&15), lanes<32: cell value is a[g][0] (row = bb*4 -> q=bb, reg 0)
    if(lane < 32){
        float iv = a[0][0]*inv_sc + bfh(gg,0);
        float fv = a[1][0]*inv_sc + bfh(gg,1);
        float gv = a[2][0]*inv_sc + bfh(gg,2);
        float ov = a[3][0]*inv_sc + bfh(gg,3);
        float cn = sigf_(fv)*cc + sigf_(iv)*tanhf2_(gv);
        cc = cn;
        float hv = sigf_(ov)*tanhf2_(cn);
        *hs_ptr = hv;
        unsigned int d8 = __builtin_amdgcn_cvt_pk_fp8_f32(hv*16.f, hv*16.f, 0u, false) & 0xFFu;
        *hpub = (unsigned char)d8;
    }
    BAR_LDS();   // h(t) published
}

// ---------------- persistent biLSTM: 64 blocks x 1024 threads (16 waves, 4/SIMD) ----------------
// R11 stagger kept; R12: operand-swapped MFMA removes the wl LDS round-trip (8 DS ops/step/wave).
__global__ __launch_bounds__(1024,4) void k_lstm_all(const float* whhf, const float* whhr,
        const unsigned short* gxb, float* hseq)
{
    int bid = blockIdx.x;        // 0..63
    int dir = bid >> 5;
    int bgrp = bid & 31;         // batches bgrp*2, bgrp*2+1
    int tid = threadIdx.x;
    int w16  = tid >> 6;         // wave 0..15: units w16*16..w16*16+15
    int lane = tid & 63;
    int q    = lane >> 4;
    int l16  = lane & 15;
    int bb   = lane >> 4;        // (lane<32) cell batch 0..1
    int u    = lane & 15;        // (lane<32) cell unit-in-wave

    __shared__ __align__(16) unsigned char hlds[2][16*272];   // [buf][row][unit] fp8; batch b at ROW 4b, rest 0

    const float* whh = dir ? whhr : whhf;

    // one-time: pack weight slice as K=128 fp8 fragments (B-operand: col=l16=unit, k=ki*128+q*32).
    int8v wreg[4][2];   // 64 VGPRs
    #pragma unroll
    for(int g=0; g<4; g++){
        const float* rp = whh + (size_t)(g*H_ + w16*16 + l16)*H_;
        #pragma unroll
        for(int ki=0; ki<2; ki++){
            const float* p = rp + ki*128 + q*32;
            int8v acc;
            #pragma unroll
            for(int wd=0; wd<8; wd++){
                unsigned int d = 0;
                d = __builtin_amdgcn_cvt_pk_fp8_f32(p[wd*4+0]*64.f, p[wd*4+1]*64.f, d, false);
                d = __builtin_amdgcn_cvt_pk_fp8_f32(p[wd*4+2]*64.f, p[wd*4+3]*64.f, d, true);
                acc[wd] = (int)d;
            }
            wreg[g][ki] = acc;
        }
    }

    for(int i = tid; i < 2*16*272/4; i += 1024) ((unsigned int*)hlds)[i] = 0;
    __syncthreads();

    // phase-stagger (R11-verified): alternate priority within each SIMD
    if(((w16 ^ (w16 >> 2)) & 1)) __builtin_amdgcn_s_setprio(1);

    const float inv_sc = 1.0f/1024.f;   // w x64, h x16
    float cc = 0.f;

    int s0 = dir ? (S_-1) : 0;
    // gates: idx = (((dir*128+s)*32 + bgrp)*16 + w16)*128 + lane*4 (uint2 = this cell's 4 gates)
    long gstep = dir ? -65536L : 65536L;
    const unsigned short* gp = gxb + ((size_t)((dir*128 + s0)*32 + bgrp))*2048 + w16*128 + lane*4;
    long hstep = dir ? -(long)(B_*H_) : (long)(B_*H_);
    float* hp = hseq + (((size_t)dir*S_ + s0)*B_ + bgrp*2 + bb)*H_ + w16*16 + u;

    // publish: batch bb -> hlds row 4*bb (rows 1-3,5-15 stay zero)
    unsigned char* hpw0 = &hlds[0][(bb*4)*272 + w16*16 + u];
    unsigned char* hpw1 = &hlds[1][(bb*4)*272 + w16*16 + u];

    uint2 P = *(const uint2*)gp; gp += gstep;
    uint2 Q;

    for(int t=0; t<S_; t+=2){
        // prefetch step t+1's gates (in flight across step A)
        Q = *(const uint2*)gp; gp += gstep;
        lstm_step16w(&hlds[0][0], hpw1, wreg, l16, q, lane, P, cc, hp, inv_sc);
        hp += hstep;
        // prefetch step t+2 (last iter lands 1 s-slot outside slice, inside gxb: harmless)
        P = *(const uint2*)gp; gp += gstep;
        lstm_step16w(&hlds[1][0], hpw0, wreg, l16, q, lane, Q, cc, hp, inv_sc);
        hp += hstep;
    }
}

// ---------------- emissions: block = 8 (s,b) pairs, h staged in LDS ----------------
__global__ __launch_bounds__(256) void k_em(const float* hseq, const float* lw, const float* lb, float* em){
    __shared__ __align__(16) float hb[8][516];   // +4 pad
    int sb0 = blockIdx.x*8;
    int tid = threadIdx.x;
    for(int i = tid; i < 1024; i += 256){
        int p = i >> 7, r = i & 127;
        int sb = sb0 + p, s = sb >> 6, b = sb & 63;
        const float* src = (r < 64) ? (hseq + (((size_t)0*S_+s)*B_+b)*H_ + r*4)
                                    : (hseq + (((size_t)1*S_+s)*B_+b)*H_ + (r-64)*4);
        *(float4*)&hb[p][r*4] = *(const float4*)src;
    }
    __syncthreads();
    if(tid < 200){
        int p = tid / 25, nc = tid % 25;
        const float4* wv = (const float4*)(lw + (size_t)nc*2*H_);
        const float4* hv = (const float4*)&hb[p][0];
        float acc = lb[nc];
        #pragma unroll 16
        for(int k=0;k<128;k++){ float4 a=hv[k], ww=wv[k]; acc += a.x*ww.x + a.y*ww.y + a.z*ww.z + a.w*ww.w; }
        em[(size_t)(sb0+p)*NC_ + nc] = acc;
    }
}

// ---------------- CRF NLL: one block = one WAVE (64 threads) per batch, no barriers ----------------
__global__ void k_crf(const float* em, const int* tag, const void* mask,
                      const float* st, const float* et, const float* tr, float* out){
    __shared__ float trs[NC_*NC_];
    int b = blockIdx.x, tid = threadIdx.x;
    for(int i=tid;i<NC_*NC_;i+=64) trs[i]=tr[i];
    unsigned int first = *(const unsigned int*)mask;
    int ml;  // 0=int32, 1=uint8, 2=float32
    if(first == 1u) ml = 0;
    else if(first == 0x3F800000u) ml = 2;
    else ml = 1;
    __syncthreads();

    // gold path score
    float part = 0.f; int cnt = 0;
    for(int s = tid; s < S_; s += 64){
        float mkv;
        {
            int off = b*S_ + s;
            if(ml==0)      mkv = ((const int*)mask)[off] ? 1.f : 0.f;
            else if(ml==1) mkv = ((const unsigned char*)mask)[off] ? 1.f : 0.f;
            else           mkv = ((const float*)mask)[off];
        }
        cnt += (mkv != 0.f) ? 1 : 0;
        if(s == 0){
            int t0 = tag[b*S_];
            part += st[t0] + em[((size_t)0*B_ + b)*NC_ + t0];
        } else {
            int tp = tag[b*S_ + s-1], tc = tag[b*S_ + s];
            part += mkv * (trs[tp*NC_ + tc] + em[((size_t)s*B_ + b)*NC_ + tc]);
        }
    }
    for(int o=32;o>0;o>>=1){ part += __shfl_down(part, o); cnt += __shfl_down(cnt, o); }
    float score = 0.f;
    int len = __shfl(cnt, 0);
    float score0 = __shfl(part, 0);
    if(tid == 0) score = score0 + et[ tag[b*S_ + len-1] ];

    // E columns in registers
    float Ecol[NC_];
    if(tid < NC_){
        #pragma unroll
        for(int i=0;i<NC_;i++) Ecol[i] = __expf(trs[i*NC_+tid]);
    } else {
        #pragma unroll
        for(int i=0;i<NC_;i++) Ecol[i] = 0.f;
    }

    float alpha = (tid < NC_) ? (st[tid] + em[((size_t)0*B_ + b)*NC_ + tid]) : -1e30f;
    float em_n = (tid < NC_) ? em[((size_t)1*B_ + b)*NC_ + tid] : 0.f;

    for(int s=1;s<S_;s++){
        float em_c = em_n;
        if(s+1 < S_) em_n = (tid < NC_) ? em[((size_t)(s+1)*B_ + b)*NC_ + tid] : 0.f;
        float mkv;
        {
            int off = b*S_ + s;
            if(ml==0)      mkv = ((const int*)mask)[off] ? 1.f : 0.f;
            else if(ml==1) mkv = ((const unsigned char*)mask)[off] ? 1.f : 0.f;
            else           mkv = ((const float*)mask)[off];
        }
        float v = alpha;
        #pragma unroll
        for(int o=16;o>0;o>>=1) v = fmaxf(v, __shfl_down(v, o));
        float m = __shfl(v, 0);
        float a = (tid < NC_) ? __expf(alpha - m) : 0.f;
        float S0 = 0.f, S1 = 0.f;
        #pragma unroll
        for(int i=0;i<24;i+=2){ S0 += __shfl(a, i) * Ecol[i]; S1 += __shfl(a, i+1) * Ecol[i+1]; }
        S0 += __shfl(a, 24) * Ecol[24];
        float nxt = m + __logf(S0 + S1) + em_c;
        if(tid < NC_ && mkv != 0.f) alpha = nxt;
    }

    float v = (tid < NC_) ? (alpha + et[tid]) : -1e30f;
    float m2 = v;
    #pragma unroll
    for(int o=16;o>0;o>>=1) m2 = fmaxf(m2, __shfl_down(m2, o));
    m2 = __shfl(m2, 0);
    float e = (tid < NC_) ? __expf(v - m2) : 0.f;
    #pragma unroll
    for(int o=16;o>0;o>>=1) e += __shfl_down(e, o);
    if(tid == 0){
        float logZ = m2 + __logf(e);
        atomicAdd(out, logZ - score);
    }
}

extern "C" void kernel_launch(void* const* d_in, const int* in_sizes, int n_in,
                              void* d_out, int out_size, void* d_ws, size_t ws_size,
                              hipStream_t stream) {
    const float* word_table = (const float*)d_in[0];
    const float* char_table = (const float*)d_in[1];
    const float* conv_w     = (const float*)d_in[2];
    const float* conv_b     = (const float*)d_in[3];
    const float* w_ih_f     = (const float*)d_in[4];
    const float* w_hh_f     = (const float*)d_in[5];
    const float* b_f        = (const float*)d_in[6];
    const float* w_ih_r     = (const float*)d_in[7];
    const float* w_hh_r     = (const float*)d_in[8];
    const float* b_r        = (const float*)d_in[9];
    const float* lin_w      = (const float*)d_in[10];
    const float* lin_b      = (const float*)d_in[11];
    const float* start_t    = (const float*)d_in[12];
    const float* end_t      = (const float*)d_in[13];
    const float* trans      = (const float*)d_in[14];
    const int*   sent       = (const int*)d_in[15];
    const int*   word       = (const int*)d_in[16];
    const int*   tag        = (const int*)d_in[17];
    const void*  mask       = d_in[18];
    float* out = (float*)d_out;

    char* ws = (char*)d_ws;
    unsigned short* feat  = (unsigned short*)ws;                 // 8192*352*2   = 5,767,168 B
    unsigned short* wpack = (unsigned short*)(ws + 5767168);     // 2048*352*2   = 1,441,792 B
    unsigned short* gxb   = (unsigned short*)(ws + 5767168 + 1441792);           // 33,554,432 B
    float* hseq = (float*)(ws + 5767168 + 1441792 + 33554432);   // 16,777,216 B
    float* em   = (float*)(ws + 5767168 + 1441792 + 33554432 + 16777216);        // 204,800 f

    k_prep<<<dim3(6273), 256, 0, stream>>>(char_table, word, conv_w, conv_b,
                                           word_table, sent, w_ih_f, w_ih_r, out, feat, wpack);
    k_gemm<<<dim3(B_*S_/128, NG_/128), 256, 0, stream>>>(feat, wpack, b_f, b_r, gxb);
    k_lstm_all<<<dim3(64), 1024, 0, stream>>>(w_hh_f, w_hh_r, gxb, hseq);
    k_em<<<dim3(S_*B_/8), 256, 0, stream>>>(hseq, lin_w, lin_b, em);
    k_crf<<<dim3(B_), 64, 0, stream>>>(em, tag, mask, start_t, end_t, trans, out);
}